// Round 11
// baseline (402.761 us; speedup 1.0000x reference)
//
#include <hip/hip_runtime.h>

typedef __attribute__((ext_vector_type(8))) short short8v;   // 8 bf16 (fallback)
typedef __attribute__((ext_vector_type(8))) __fp16 h8v;      // 8 f16
typedef __attribute__((ext_vector_type(2))) __fp16 h2v;      // 2 f16
typedef __attribute__((ext_vector_type(4))) float f32x4;

__device__ inline unsigned short f2bf(float f) {
    unsigned u = __builtin_bit_cast(unsigned, f);
    return (unsigned short)((u + 0x7FFFu + ((u >> 16) & 1u)) >> 16);   // RNE
}

__device__ inline float dot2(h2v a, h2v b, float c) {
#if __has_builtin(__builtin_amdgcn_fdot2)
    return __builtin_amdgcn_fdot2(a, b, c, false);
#else
    return c + (float)a[0] * (float)b[0] + (float)a[1] * (float)b[1];
#endif
}
__device__ inline h2v pk2h(float a, float b) {
#if __has_builtin(__builtin_amdgcn_cvt_pkrtz)
    return __builtin_bit_cast(h2v, __builtin_amdgcn_cvt_pkrtz(a, b));
#else
    h2v r; r[0] = (__fp16)a; r[1] = (__fp16)b; return r;
#endif
}
__device__ inline float fexp2(float x) {
#if __has_builtin(__builtin_amdgcn_exp2f)
    return __builtin_amdgcn_exp2f(x);
#else
    return __expf(x * 0.6931471805599453f);
#endif
}
// select producer register (rSel) from two packed-pair shuffles and build an h2v
__device__ inline h2v sel_pack(int x01, int x23, int y01, int y23, int rSel) {
    unsigned sx = (unsigned)(rSel < 2 ? x01 : x23);
    unsigned sy = (unsigned)(rSel < 2 ? y01 : y23);
    unsigned ex = (rSel & 1) ? (sx >> 16) : (sx & 0xffffu);
    unsigned ey = (rSel & 1) ? (sy >> 16) : (sy & 0xffffu);
    return __builtin_bit_cast(h2v, (unsigned)(ex | (ey << 16)));
}

// ---------------- prep 1: qkv_w -> f16 B-fragments in ws ----------------
__global__ __launch_bounds__(256) void prep_weights(const float* __restrict__ qkv_w,
                                                    __fp16* __restrict__ wf) {
    int it = blockIdx.x * 256 + threadIdx.x;      // 1536 items
    if (it >= 1536) return;
    int l = it & 63, frag = it >> 6;
    int which = frag >> 3, nt = (frag >> 1) & 3, kst = frag & 1;
    const float* src = qkv_w + (which * 64 + nt * 16 + (l & 15)) * 64 + kst * 32 + (l >> 4) * 8;
    h8v pk;
    #pragma unroll
    for (int j = 0; j < 8; ++j) pk[j] = (__fp16)src[j];
    *reinterpret_cast<h8v*>(wf + it * 8) = pk;
}

// ---------------- prep 2: x (b,c,y,x) fp32 -> two pre-rolled (b,y,x,128) f16 buffers ----------------
// xbf_s[b][y'][x][c'] = x[b][(c'+s)%128][(y'+s)%192][x]; pixel stride 256 B (line-aligned)
__global__ __launch_bounds__(256) void prep_x(const float* __restrict__ x,
                                              __fp16* __restrict__ xbf0,
                                              __fp16* __restrict__ xbf2) {
    const int xt = blockIdx.x;   // 0..5 (32-wide tiles)
    const int y  = blockIdx.y;
    const int b  = blockIdx.z;
    const int x0 = xt * 32;
    __shared__ float buf[128 * 33];

    for (int it = threadIdx.x; it < 1024; it += 256) {
        int c = it >> 3, xq = it & 7;
        const float4 v = *reinterpret_cast<const float4*>(
            x + ((b * 128 + c) * 192 + y) * 192 + x0 + xq * 4);
        float* d = &buf[c * 33 + xq * 4];
        d[0] = v.x; d[1] = v.y; d[2] = v.z; d[3] = v.w;
    }
    __syncthreads();

    #pragma unroll
    for (int si = 0; si < 2; ++si) {
        const int s = si * 2;
        __fp16* dst = si ? xbf2 : xbf0;
        int ydst = y - s; if (ydst < 0) ydst += 192;
        for (int it = threadIdx.x; it < 512; it += 256) {
            int xl = it >> 4, c8 = it & 15;
            h8v pk;
            #pragma unroll
            for (int j = 0; j < 8; ++j) {
                int c = (s + c8 * 8 + j) & 127;
                pk[j] = (__fp16)buf[c * 33 + xl];
            }
            *reinterpret_cast<h8v*>(dst + (((size_t)(b * 192 + ydst) * 192) + x0 + xl) * 128 + c8 * 8) = pk;
        }
    }
}

// ---------------- main: 4-window strip per block ----------------
template<int SHIFT, bool ACCUM>
__global__ __launch_bounds__(256) void swin_main(
    const __fp16* __restrict__ xbf,   // pre-rolled (b,y,x,128) f16 for this shift
    const __fp16* __restrict__ wfrag,
    const float* __restrict__ lepe_w,
    const float* __restrict__ bias_table,
    float* __restrict__ out)
{
    const int bx = blockIdx.x;                 // wy*12 + strip
    const int wy = bx / 12, strip = bx % 12;
    const int half = blockIdx.y, b = blockIdx.z;
    const int tid = threadIdx.x;
    const int w = tid >> 6, l = tid & 63;      // wave = window within strip

    // pool phase A: x strip [108 pos][64 ch] (6912 f16); phase B: wave-private v [4][36][64] (9216 f16)
    __shared__ __fp16 pool[9216];              // 18432 B
    __shared__ __fp16 ks[64 * 64];             // k [tok][ch' head-major] swizzled (8192 B)
    __shared__ float  bias_s[392];             // pre-scaled by log2e (1568 B)
    __shared__ __fp16 lepe_s[576];             // layout [h][3x3 j][8 d] (1152 B)
    // LDS total = 29344 B -> 5 blocks/CU (20 waves)

    for (int i = tid; i < 392; i += 256) bias_s[i] = bias_table[i] * 1.4426950408889634f;
    for (int i = tid; i < 576; i += 256) {
        int d = i & 7, rest = i >> 3;
        int j = rest % 9, h = rest / 9;
        lepe_s[i] = (__fp16)lepe_w[(d * 8 + h) * 9 + j];
    }

    // ---- stage strip from pre-rolled buffer (fully aligned 16B reads) ----
    const int ry0 = wy * 4 - 1, rx0 = strip * 16 - 1;
    for (int it = tid; it < 864; it += 256) {
        const int pos = it >> 3, slot = it & 7;
        const int py = pos / 18, px = pos - py * 18;
        const int ry = ry0 + py, rx = rx0 + px;
        h8v val;
        #pragma unroll
        for (int j = 0; j < 8; ++j) val[j] = (__fp16)0.f;
        if (ry >= 0 && ry < 192 && rx >= 0 && rx < 192) {
            const int srcslot = slot ^ (pos & 7);
            val = *reinterpret_cast<const h8v*>(
                xbf + (((size_t)(b * 192 + ry) * 192) + rx) * 128 + half * 64 + srcslot * 8);
        }
        *reinterpret_cast<h8v*>(&pool[pos * 64 + slot * 8]) = val;
    }
    __syncthreads();

    // ---- A fragments (swizzled reads from strip) ----
    const int tok16 = l & 15, g = l >> 4;
    h8v Aq[2], Av[3][2];
    {
        const int posq = (1 + (tok16 >> 2)) * 18 + w * 4 + 1 + (tok16 & 3);
        #pragma unroll
        for (int kst = 0; kst < 2; ++kst) {
            int chunk = (kst * 4 + g) ^ (posq & 7);
            Aq[kst] = *reinterpret_cast<const h8v*>(&pool[posq * 64 + chunk * 8]);
        }
        #pragma unroll
        for (int mt = 0; mt < 3; ++mt) {
            int t = mt * 16 + tok16;
            int posv = (t < 36) ? ((t / 6) * 18 + w * 4 + (t % 6)) : 0;
            #pragma unroll
            for (int kst = 0; kst < 2; ++kst) {
                int chunk = (kst * 4 + g) ^ (posv & 7);
                Av[mt][kst] = *reinterpret_cast<const h8v*>(&pool[posv * 64 + chunk * 8]);
            }
        }
    }
    __syncthreads();   // strip dead; pool becomes wave-private v

    // attention-role constants (needed for q shfl gather)
    const int h = l >> 3, tqp = l & 7;
    const int pA = ((tqp >> 2) << 4) + h;      // producer lane for q0, even d
    const int rSel = tqp & 3;                  // producer register
    h2v q0p[4], q1p[4];                        // q packed per d-pair, pre-scaled by 8^-1/2*log2e

    // ---- MFMA + scatter; channels stored head-major ch'=(ch&7)*8+(ch>>3) ----
    #pragma unroll
    for (int nt = 0; nt < 4; ++nt) {
        h8v Bq[2], Bk[2], Bv[2];
        #pragma unroll
        for (int kst = 0; kst < 2; ++kst) {
            Bq[kst] = *reinterpret_cast<const h8v*>(wfrag + (((0 * 8 + nt * 2 + kst) * 64 + l) * 8));
            Bk[kst] = *reinterpret_cast<const h8v*>(wfrag + (((1 * 8 + nt * 2 + kst) * 64 + l) * 8));
            Bv[kst] = *reinterpret_cast<const h8v*>(wfrag + (((2 * 8 + nt * 2 + kst) * 64 + l) * 8));
        }
        f32x4 aQ = {0.f,0.f,0.f,0.f}, aK = {0.f,0.f,0.f,0.f};
        f32x4 aV[3];
        #pragma unroll
        for (int mt = 0; mt < 3; ++mt) aV[mt] = (f32x4){0.f,0.f,0.f,0.f};
        #pragma unroll
        for (int kst = 0; kst < 2; ++kst) {
            aQ = __builtin_amdgcn_mfma_f32_16x16x32_f16(Aq[kst], Bq[kst], aQ, 0, 0, 0);
            aK = __builtin_amdgcn_mfma_f32_16x16x32_f16(Aq[kst], Bk[kst], aK, 0, 0, 0);
            #pragma unroll
            for (int mt = 0; mt < 3; ++mt)
                aV[mt] = __builtin_amdgcn_mfma_f32_16x16x32_f16(Av[mt][kst], Bv[kst], aV[mt], 0, 0, 0);
        }

        // ---- q gather via in-wave shfl (replaces qs LDS buffer) ----
        {
            const float QS = 0.5101293f;   // 8^-0.5 * log2(e)
            int pk01 = (int)__builtin_bit_cast(unsigned, pk2h(aQ[0] * QS, aQ[1] * QS));
            int pk23 = (int)__builtin_bit_cast(unsigned, pk2h(aQ[2] * QS, aQ[3] * QS));
            int a01 = __shfl(pk01, pA),      a23 = __shfl(pk23, pA);
            int b01 = __shfl(pk01, pA + 8),  b23 = __shfl(pk23, pA + 8);
            int c01 = __shfl(pk01, pA + 32), c23 = __shfl(pk23, pA + 32);
            int d01 = __shfl(pk01, pA + 40), d23 = __shfl(pk23, pA + 40);
            q0p[nt] = sel_pack(a01, a23, b01, b23, rSel);
            q1p[nt] = sel_pack(c01, c23, d01, d23, rSel);
        }

        const int ch  = nt * 16 + tok16;
        const int chp = (ch & 7) * 8 + (ch >> 3);
        #pragma unroll
        for (int r = 0; r < 4; ++r) {
            const int ktok = w * 16 + 4 * g + r;
            const int pb = (((chp >> 3) ^ (ktok & 7)) * 8 + (chp & 7));
            ks[ktok * 64 + pb] = (__fp16)aK[r];
        }
        #pragma unroll
        for (int mt = 0; mt < 3; ++mt)
            #pragma unroll
            for (int r = 0; r < 4; ++r) {
                const int t = mt * 16 + 4 * g + r;       // linear token in wave's 6x6 patch
                if (t < 36) {
                    const int pb = (((chp >> 3) ^ (t & 7)) * 8 + (chp & 7));
                    pool[(w * 36 + t) * 64 + pb] = (__fp16)aV[mt][r];
                }
            }
    }
    __syncthreads();

    // ---- attention + lepe + store: wave = window, lane = (h, tqp), 2 query tokens/lane ----
    {
        const int qy0 = tqp >> 2, qx0 = tqp & 3;   // tq0 = tqp; tq1 = tqp+8 -> qy0+2, qx0
        const __fp16* vv = &pool[w * 36 * 64];

        // output indices + RMW prefetch (latency hides under QK/PV)
        const int ox = strip * 16 + w * 4 + qx0;
        int oy0 = wy * 4 + qy0 + SHIFT;     if (oy0 >= 192) oy0 -= 192;
        int oy1 = wy * 4 + qy0 + 2 + SHIFT; if (oy1 >= 192) oy1 -= 192;
        const int ddelta = (oy1 - oy0) * 192;
        int idx0[8];
        float prev0[8], prev1[8];
        #pragma unroll
        for (int d = 0; d < 8; ++d) {
            const int oc = half * 64 + ((d * 8 + h + SHIFT) & 63);
            idx0[d] = ((b * 128 + oc) * 192 + oy0) * 192 + ox;
            if (ACCUM) { prev0[d] = out[idx0[d]]; prev1[d] = out[idx0[d] + ddelta]; }
        }

        // scores tightly bounded: exp2 without max-subtraction is safe
        h2v scp0[8], scp1[8];
        float den0 = 0.f, den1 = 0.f;
        #pragma unroll
        for (int tkp = 0; tkp < 8; ++tkp) {
            float e0[2], e1[2];
            #pragma unroll
            for (int u = 0; u < 2; ++u) {
                const int tk = tkp * 2 + u;
                const int kt = w * 16 + tk;
                h8v kr = *reinterpret_cast<const h8v*>(&ks[kt * 64 + (h ^ (kt & 7)) * 8]);
                const h2v* kp = reinterpret_cast<const h2v*>(&kr);
                float s0 = 0.f, s1 = 0.f;
                #pragma unroll
                for (int i = 0; i < 4; ++i) { s0 = dot2(q0p[i], kp[i], s0); s1 = dot2(q1p[i], kp[i], s1); }
                const int ky = tk >> 2, kx = tk & 3;
                s0 += bias_s[((qy0 - ky + 3) * 7 + (qx0 - kx + 3)) * 8 + h];
                s1 += bias_s[((qy0 + 2 - ky + 3) * 7 + (qx0 - kx + 3)) * 8 + h];
                e0[u] = fexp2(s0); e1[u] = fexp2(s1);
            }
            den0 += e0[0] + e0[1]; den1 += e1[0] + e1[1];
            scp0[tkp] = pk2h(e0[0], e0[1]);
            scp1[tkp] = pk2h(e1[0], e1[1]);
        }
        const float inv0 = 1.f / den0, inv1 = 1.f / den1;
        const h2v ip0 = pk2h(inv0, inv0), ip1 = pk2h(inv1, inv1);

        // ---- PV packed f16 (v_pk_fma_f16), normalized convex weights ----
        h2v o0pk[4], o1pk[4];
        #pragma unroll
        for (int j = 0; j < 4; ++j) { o0pk[j] = pk2h(0.f, 0.f); o1pk[j] = pk2h(0.f, 0.f); }
        #pragma unroll
        for (int tkp = 0; tkp < 8; ++tkp) {
            const h2v w0 = scp0[tkp] * ip0;
            const h2v w1 = scp1[tkp] * ip1;
            #pragma unroll
            for (int u = 0; u < 2; ++u) {
                const int tk = tkp * 2 + u;
                const int t = (1 + (tk >> 2)) * 6 + 1 + (tk & 3);
                h8v vr = *reinterpret_cast<const h8v*>(&vv[t * 64 + (h ^ (t & 7)) * 8]);
                const h2v* vp = reinterpret_cast<const h2v*>(&vr);
                h2v b0; b0[0] = w0[u]; b0[1] = w0[u];
                h2v b1; b1[0] = w1[u]; b1[1] = w1[u];
                #pragma unroll
                for (int j = 0; j < 4; ++j) {
                    o0pk[j] += b0 * vp[j];
                    o1pk[j] += b1 * vp[j];
                }
            }
        }

        // ---- lepe packed f16: lw layout [h][j][8 d] ----
        #pragma unroll
        for (int dy = 0; dy < 3; ++dy)
            #pragma unroll
            for (int dx = 0; dx < 3; ++dx) {
                const int ta = (qy0 + dy) * 6 + qx0 + dx;
                const int tb = ta + 12;                      // +2 rows for token 1
                h8v v0 = *reinterpret_cast<const h8v*>(&vv[ta * 64 + (h ^ (ta & 7)) * 8]);
                h8v v1 = *reinterpret_cast<const h8v*>(&vv[tb * 64 + (h ^ (tb & 7)) * 8]);
                h8v lw = *reinterpret_cast<const h8v*>(&lepe_s[(h * 9 + dy * 3 + dx) * 8]);
                const h2v* v0p = reinterpret_cast<const h2v*>(&v0);
                const h2v* v1p = reinterpret_cast<const h2v*>(&v1);
                const h2v* lwp = reinterpret_cast<const h2v*>(&lw);
                #pragma unroll
                for (int j = 0; j < 4; ++j) {
                    o0pk[j] += v0p[j] * lwp[j];
                    o1pk[j] += v1p[j] * lwp[j];
                }
            }

        #pragma unroll
        for (int d = 0; d < 8; ++d) {
            const float a0 = (float)o0pk[d >> 1][d & 1];
            const float a1 = (float)o1pk[d >> 1][d & 1];
            if (ACCUM) { out[idx0[d]] = prev0[d] + a0; out[idx0[d] + ddelta] = prev1[d] + a1; }
            else       { out[idx0[d]] = a0;            out[idx0[d] + ddelta] = a1; }
        }
    }
}

// ---------------- fallback (round-3 kernel, bf16; used only if ws too small) ----------------
template<int SHIFT, bool ACCUM>
__global__ __launch_bounds__(256) void swin_fb(
    const float* __restrict__ x, const float* __restrict__ qkv_w,
    const float* __restrict__ lepe_w, const float* __restrict__ bias_table,
    float* __restrict__ out)
{
    const int C = 128, HH = 192, WW = 192;
    const int win = blockIdx.x, wy = win / 48, wx = win % 48;
    const int half = blockIdx.y, b = blockIdx.z, tid = threadIdx.x;
    __shared__ short xpA[8 * 64 * 8];
    __shared__ float vs[64 * 37], qsf[64 * 17], ksf[64 * 17];
    __shared__ float bias_s[392], lepe_s[576];
    const int ys0 = wy * 4, xs0 = wx * 4;
    for (int i = tid; i < 392; i += 256) bias_s[i] = bias_table[i];
    for (int i = tid; i < 576; i += 256) lepe_s[i] = lepe_w[i];
    for (int item = tid; item < 512; item += 256) {
        const int slot = item >> 6, l = item & 63, kst = slot & 1;
        int p = 0; bool tvalid = true;
        if (slot < 6) { int t48 = (slot >> 1) * 16 + (l & 15); tvalid = (t48 < 36); p = t48; }
        else { int ti = l & 15; p = (1 + (ti >> 2)) * 6 + 1 + (ti & 3); }
        const int c0 = kst * 32 + (l >> 4) * 8;
        short8v pk;
        #pragma unroll
        for (int j = 0; j < 8; ++j) pk[j] = 0;
        if (tvalid) {
            int py = p / 6, px = p - py * 6;
            int ry = ys0 - 1 + py, rx = xs0 - 1 + px;
            if (ry >= 0 && ry < HH && rx >= 0 && rx < WW) {
                int oy = ry + SHIFT; if (oy >= HH) oy -= HH;
                #pragma unroll
                for (int j = 0; j < 8; ++j) {
                    int oc = half * 64 + c0 + j + SHIFT; if (oc >= C) oc -= C;
                    pk[j] = (short)f2bf(x[((b * C + oc) * HH + oy) * WW + rx]);
                }
            }
        }
        *reinterpret_cast<short8v*>(&xpA[item * 8]) = pk;
    }
    const int w = tid >> 6, l = tid & 63, nn = l & 15, g = l >> 4;
    short8v Bq[2], Bk[2], Bv[2];
    #pragma unroll
    for (int kst = 0; kst < 2; ++kst) {
        const int coff = kst * 32 + g * 8;
        const float* s0 = qkv_w + (w * 16 + nn) * 64 + coff;
        const float* s1 = qkv_w + (64 + w * 16 + nn) * 64 + coff;
        const float* s2 = qkv_w + (128 + w * 16 + nn) * 64 + coff;
        short8v p0, p1, p2;
        #pragma unroll
        for (int j = 0; j < 8; ++j) { p0[j] = (short)f2bf(s0[j]); p1[j] = (short)f2bf(s1[j]); p2[j] = (short)f2bf(s2[j]); }
        Bq[kst] = p0; Bk[kst] = p1; Bv[kst] = p2;
    }
    __syncthreads();
    {
        short8v Aq[2], Avf[3][2];
        #pragma unroll
        for (int kst = 0; kst < 2; ++kst)
            Aq[kst] = *reinterpret_cast<const short8v*>(&xpA[((6 + kst) * 64 + l) * 8]);
        #pragma unroll
        for (int mt = 0; mt < 3; ++mt)
            #pragma unroll
            for (int kst = 0; kst < 2; ++kst)
                Avf[mt][kst] = *reinterpret_cast<const short8v*>(&xpA[((mt * 2 + kst) * 64 + l) * 8]);
        f32x4 aQ = {0,0,0,0}, aK = {0,0,0,0}; f32x4 aV[3];
        #pragma unroll
        for (int mt = 0; mt < 3; ++mt) aV[mt] = (f32x4){0,0,0,0};
        #pragma unroll
        for (int kst = 0; kst < 2; ++kst) {
            aQ = __builtin_amdgcn_mfma_f32_16x16x32_bf16(Aq[kst], Bq[kst], aQ, 0, 0, 0);
            aK = __builtin_amdgcn_mfma_f32_16x16x32_bf16(Aq[kst], Bk[kst], aK, 0, 0, 0);
            #pragma unroll
            for (int mt = 0; mt < 3; ++mt)
                aV[mt] = __builtin_amdgcn_mfma_f32_16x16x32_bf16(Avf[mt][kst], Bv[kst], aV[mt], 0, 0, 0);
        }
        const int ch = w * 16 + nn;
        #pragma unroll
        for (int r = 0; r < 4; ++r) { qsf[ch * 17 + g * 4 + r] = aQ[r]; ksf[ch * 17 + g * 4 + r] = aK[r]; }
        #pragma unroll
        for (int mt = 0; mt < 3; ++mt)
            #pragma unroll
            for (int r = 0; r < 4; ++r) { int tok = mt * 16 + g * 4 + r; if (tok < 36) vs[ch * 37 + tok] = aV[mt][r]; }
    }
    __syncthreads();
    {
        const int tq = tid & 15, h = (tid >> 4) & 7, dh = tid >> 7;
        const int qy = tq >> 2, qx = tq & 3;
        const float scale = 0.35355339059327373f;
        float qreg[8];
        #pragma unroll
        for (int d = 0; d < 8; ++d) qreg[d] = qsf[(d * 8 + h) * 17 + tq] * scale;
        float sc[16]; float m = -1e30f;
        #pragma unroll
        for (int tk = 0; tk < 16; ++tk) {
            float s = 0.f;
            #pragma unroll
            for (int d = 0; d < 8; ++d) s += qreg[d] * ksf[(d * 8 + h) * 17 + tk];
            s += bias_s[((qy - (tk >> 2) + 3) * 7 + (qx - (tk & 3) + 3)) * 8 + h];
            sc[tk] = s; m = fmaxf(m, s);
        }
        float den = 0.f;
        #pragma unroll
        for (int tk = 0; tk < 16; ++tk) { sc[tk] = __expf(sc[tk] - m); den += sc[tk]; }
        const float inv = 1.f / den;
        float lw[4][9];
        #pragma unroll
        for (int dd = 0; dd < 4; ++dd) {
            int ch = (dh * 4 + dd) * 8 + h;
            #pragma unroll
            for (int j = 0; j < 9; ++j) lw[dd][j] = lepe_s[ch * 9 + j];
        }
        float o[4] = {0,0,0,0};
        #pragma unroll
        for (int tk = 0; tk < 16; ++tk) {
            int p = (1 + (tk >> 2)) * 6 + 1 + (tk & 3); float s = sc[tk];
            #pragma unroll
            for (int dd = 0; dd < 4; ++dd) o[dd] += s * vs[((dh * 4 + dd) * 8 + h) * 37 + p];
        }
        int oy = ys0 + qy + SHIFT; if (oy >= HH) oy -= HH;
        const int irx = xs0 + qx;
        #pragma unroll
        for (int dd = 0; dd < 4; ++dd) {
            const int ch = (dh * 4 + dd) * 8 + h;
            float val = o[dd] * inv;
            #pragma unroll
            for (int dy = 0; dy < 3; ++dy)
                #pragma unroll
                for (int dx = 0; dx < 3; ++dx)
                    val += vs[ch * 37 + (qy + dy) * 6 + (qx + dx)] * lw[dd][dy * 3 + dx];
            const int oc = half * 64 + ((ch + SHIFT) & 63);
            const int oidx = ((b * C + oc) * HH + oy) * WW + irx;
            if (ACCUM) out[oidx] += val; else out[oidx] = val;
        }
    }
}

extern "C" void kernel_launch(void* const* d_in, const int* in_sizes, int n_in,
                              void* d_out, int out_size, void* d_ws, size_t ws_size,
                              hipStream_t stream) {
    const float* x          = (const float*)d_in[0];
    const float* qkv_w      = (const float*)d_in[1];
    const float* lepe_w     = (const float*)d_in[2];
    const float* bias_table = (const float*)d_in[3];
    float* out = (float*)d_out;

    const size_t XBF_BYTES = 8UL * 192 * 192 * 128 * 2;        // 75,497,472
    const size_t NEED = 32768 + 2 * XBF_BYTES;

    if (ws_size >= NEED) {
        __fp16* wf   = (__fp16*)d_ws;
        __fp16* xbf0 = (__fp16*)((char*)d_ws + 32768);
        __fp16* xbf2 = (__fp16*)((char*)d_ws + 32768 + XBF_BYTES);
        prep_weights<<<6, 256, 0, stream>>>(qkv_w, wf);
        prep_x<<<dim3(6, 192, 8), 256, 0, stream>>>(x, xbf0, xbf2);
        dim3 grid(576, 2, 8);
        swin_main<0, false><<<grid, 256, 0, stream>>>(xbf0, wf, lepe_w, bias_table, out);
        swin_main<2, true ><<<grid, 256, 0, stream>>>(xbf2, wf, lepe_w, bias_table, out);
    } else {
        dim3 grid(48 * 48, 2, 8);
        swin_fb<0, false><<<grid, 256, 0, stream>>>(x, qkv_w, lepe_w, bias_table, out);
        swin_fb<2, true ><<<grid, 256, 0, stream>>>(x, qkv_w, lepe_w, bias_table, out);
    }
}

// Round 12
// 378.056 us; speedup vs baseline: 1.0653x; 1.0653x over previous
//
#include <hip/hip_runtime.h>

typedef __attribute__((ext_vector_type(8))) short short8v;   // 8 bf16 (fallback)
typedef __attribute__((ext_vector_type(8))) __fp16 h8v;      // 8 f16
typedef __attribute__((ext_vector_type(2))) __fp16 h2v;      // 2 f16
typedef __attribute__((ext_vector_type(4))) float f32x4;

__device__ inline unsigned short f2bf(float f) {
    unsigned u = __builtin_bit_cast(unsigned, f);
    return (unsigned short)((u + 0x7FFFu + ((u >> 16) & 1u)) >> 16);   // RNE
}

__device__ inline float dot2(h2v a, h2v b, float c) {
#if __has_builtin(__builtin_amdgcn_fdot2)
    return __builtin_amdgcn_fdot2(a, b, c, false);
#else
    return c + (float)a[0] * (float)b[0] + (float)a[1] * (float)b[1];
#endif
}
__device__ inline h2v pk2h(float a, float b) {
#if __has_builtin(__builtin_amdgcn_cvt_pkrtz)
    return __builtin_bit_cast(h2v, __builtin_amdgcn_cvt_pkrtz(a, b));
#else
    h2v r; r[0] = (__fp16)a; r[1] = (__fp16)b; return r;
#endif
}
__device__ inline float fexp2(float x) {
#if __has_builtin(__builtin_amdgcn_exp2f)
    return __builtin_amdgcn_exp2f(x);
#else
    return __expf(x * 0.6931471805599453f);
#endif
}

// ---------------- prep 1: qkv_w -> f16 B-fragments in ws ----------------
__global__ __launch_bounds__(256) void prep_weights(const float* __restrict__ qkv_w,
                                                    __fp16* __restrict__ wf) {
    int it = blockIdx.x * 256 + threadIdx.x;      // 1536 items
    if (it >= 1536) return;
    int l = it & 63, frag = it >> 6;
    int which = frag >> 3, nt = (frag >> 1) & 3, kst = frag & 1;
    const float* src = qkv_w + (which * 64 + nt * 16 + (l & 15)) * 64 + kst * 32 + (l >> 4) * 8;
    h8v pk;
    #pragma unroll
    for (int j = 0; j < 8; ++j) pk[j] = (__fp16)src[j];
    *reinterpret_cast<h8v*>(wf + it * 8) = pk;
}

// ---------------- prep 2: x (b,c,y,x) fp32 -> two pre-rolled (b,y,x,128) f16 buffers ----------------
// xbf_s[b][y'][x][c'] = x[b][(c'+s)%128][(y'+s)%192][x]; pixel stride 256 B (line-aligned)
__global__ __launch_bounds__(256) void prep_x(const float* __restrict__ x,
                                              __fp16* __restrict__ xbf0,
                                              __fp16* __restrict__ xbf2) {
    const int xt = blockIdx.x;   // 0..5 (32-wide tiles)
    const int y  = blockIdx.y;
    const int b  = blockIdx.z;
    const int x0 = xt * 32;
    __shared__ float buf[128 * 33];

    for (int it = threadIdx.x; it < 1024; it += 256) {
        int c = it >> 3, xq = it & 7;
        const float4 v = *reinterpret_cast<const float4*>(
            x + ((b * 128 + c) * 192 + y) * 192 + x0 + xq * 4);
        float* d = &buf[c * 33 + xq * 4];
        d[0] = v.x; d[1] = v.y; d[2] = v.z; d[3] = v.w;
    }
    __syncthreads();

    #pragma unroll
    for (int si = 0; si < 2; ++si) {
        const int s = si * 2;
        __fp16* dst = si ? xbf2 : xbf0;
        int ydst = y - s; if (ydst < 0) ydst += 192;
        for (int it = threadIdx.x; it < 512; it += 256) {
            int xl = it >> 4, c8 = it & 15;
            h8v pk;
            #pragma unroll
            for (int j = 0; j < 8; ++j) {
                int c = (s + c8 * 8 + j) & 127;
                pk[j] = (__fp16)buf[c * 33 + xl];
            }
            *reinterpret_cast<h8v*>(dst + (((size_t)(b * 192 + ydst) * 192) + x0 + xl) * 128 + c8 * 8) = pk;
        }
    }
}

// ---------------- main: 4-window strip per block ----------------
template<int SHIFT, bool ACCUM>
__global__ __launch_bounds__(256) void swin_main(
    const __fp16* __restrict__ xbf,   // pre-rolled (b,y,x,128) f16 for this shift
    const __fp16* __restrict__ wfrag,
    const float* __restrict__ lepe_w,
    const float* __restrict__ bias_table,
    float* __restrict__ out)
{
    const int bx = blockIdx.x;                 // wy*12 + strip
    const int wy = bx / 12, strip = bx % 12;
    const int half = blockIdx.y, b = blockIdx.z;
    const int tid = threadIdx.x;
    const int w = tid >> 6, l = tid & 63;      // wave = window within strip

    // pool phase A: x strip [108 pos][64 ch]; phase B: wave-private v [4 w][36 t][64 ch]
    __shared__ __fp16 pool[9216];              // 18432 B
    __shared__ __fp16 qs[64 * 64];             // q [tok][ch' head-major] swz, pre-scaled*log2e
    __shared__ __fp16 ks[64 * 64];
    __shared__ float  bias_s[392];             // pre-scaled by log2e
    __shared__ __fp16 lepe_s[576];             // layout [h][3x3 j][8 d]
    // LDS total = 37536 B -> 4 blocks/CU

    for (int i = tid; i < 392; i += 256) bias_s[i] = bias_table[i] * 1.4426950408889634f;
    for (int i = tid; i < 576; i += 256) {
        int d = i & 7, rest = i >> 3;
        int j = rest % 9, h = rest / 9;
        lepe_s[i] = (__fp16)lepe_w[(d * 8 + h) * 9 + j];
    }

    // ---- stage strip from pre-rolled buffer (fully aligned 16B reads) ----
    const int ry0 = wy * 4 - 1, rx0 = strip * 16 - 1;
    for (int it = tid; it < 864; it += 256) {
        const int pos = it >> 3, slot = it & 7;
        const int py = pos / 18, px = pos - py * 18;
        const int ry = ry0 + py, rx = rx0 + px;
        h8v val;
        #pragma unroll
        for (int j = 0; j < 8; ++j) val[j] = (__fp16)0.f;
        if (ry >= 0 && ry < 192 && rx >= 0 && rx < 192) {
            const int srcslot = slot ^ (pos & 7);
            val = *reinterpret_cast<const h8v*>(
                xbf + (((size_t)(b * 192 + ry) * 192) + rx) * 128 + half * 64 + srcslot * 8);
        }
        *reinterpret_cast<h8v*>(&pool[pos * 64 + slot * 8]) = val;
    }
    __syncthreads();

    // ---- A fragments (swizzled reads from strip) ----
    const int tok16 = l & 15, g = l >> 4;
    h8v Aq[2], Av[3][2];
    {
        const int posq = (1 + (tok16 >> 2)) * 18 + w * 4 + 1 + (tok16 & 3);
        #pragma unroll
        for (int kst = 0; kst < 2; ++kst) {
            int chunk = (kst * 4 + g) ^ (posq & 7);
            Aq[kst] = *reinterpret_cast<const h8v*>(&pool[posq * 64 + chunk * 8]);
        }
        #pragma unroll
        for (int mt = 0; mt < 3; ++mt) {
            int t = mt * 16 + tok16;
            int posv = (t < 36) ? ((t / 6) * 18 + w * 4 + (t % 6)) : 0;
            #pragma unroll
            for (int kst = 0; kst < 2; ++kst) {
                int chunk = (kst * 4 + g) ^ (posv & 7);
                Av[mt][kst] = *reinterpret_cast<const h8v*>(&pool[posv * 64 + chunk * 8]);
            }
        }
    }
    __syncthreads();   // strip dead; pool becomes wave-private v

    // ---- MFMA + scatter; channels stored head-major ch'=(ch&7)*8+(ch>>3) ----
    #pragma unroll
    for (int nt = 0; nt < 4; ++nt) {
        h8v Bq[2], Bk[2], Bv[2];
        #pragma unroll
        for (int kst = 0; kst < 2; ++kst) {
            Bq[kst] = *reinterpret_cast<const h8v*>(wfrag + (((0 * 8 + nt * 2 + kst) * 64 + l) * 8));
            Bk[kst] = *reinterpret_cast<const h8v*>(wfrag + (((1 * 8 + nt * 2 + kst) * 64 + l) * 8));
            Bv[kst] = *reinterpret_cast<const h8v*>(wfrag + (((2 * 8 + nt * 2 + kst) * 64 + l) * 8));
        }
        f32x4 aQ = {0.f,0.f,0.f,0.f}, aK = {0.f,0.f,0.f,0.f};
        f32x4 aV[3];
        #pragma unroll
        for (int mt = 0; mt < 3; ++mt) aV[mt] = (f32x4){0.f,0.f,0.f,0.f};
        #pragma unroll
        for (int kst = 0; kst < 2; ++kst) {
            aQ = __builtin_amdgcn_mfma_f32_16x16x32_f16(Aq[kst], Bq[kst], aQ, 0, 0, 0);
            aK = __builtin_amdgcn_mfma_f32_16x16x32_f16(Aq[kst], Bk[kst], aK, 0, 0, 0);
            #pragma unroll
            for (int mt = 0; mt < 3; ++mt)
                aV[mt] = __builtin_amdgcn_mfma_f32_16x16x32_f16(Av[mt][kst], Bv[kst], aV[mt], 0, 0, 0);
        }
        const int ch  = nt * 16 + tok16;
        const int chp = (ch & 7) * 8 + (ch >> 3);
        #pragma unroll
        for (int r = 0; r < 4; ++r) {
            const int qtok = w * 16 + 4 * g + r;
            const int pb = (((chp >> 3) ^ (qtok & 7)) * 8 + (chp & 7));
            // q pre-scaled by 8^-0.5 * log2(e) so scores are in log2 units
            qs[qtok * 64 + pb] = (__fp16)(aQ[r] * 0.5101293f);
            ks[qtok * 64 + pb] = (__fp16)aK[r];
        }
        #pragma unroll
        for (int mt = 0; mt < 3; ++mt)
            #pragma unroll
            for (int r = 0; r < 4; ++r) {
                const int t = mt * 16 + 4 * g + r;       // linear token in wave's 6x6 patch
                if (t < 36) {
                    const int pb = (((chp >> 3) ^ (t & 7)) * 8 + (chp & 7));
                    pool[(w * 36 + t) * 64 + pb] = (__fp16)aV[mt][r];
                }
            }
    }
    __syncthreads();

    // ---- attention + lepe + store: wave = window, lane = (h, tq&7), 2 query tokens/lane ----
    {
        const int h = l >> 3, tqp = l & 7;
        const int qy0 = tqp >> 2, qx0 = tqp & 3;   // tq0 = tqp; tq1 = tqp+8 -> qy0+2, qx0
        const __fp16* vv = &pool[w * 36 * 64];

        // output indices + RMW prefetch (latency hides under QK/PV)
        const int ox = strip * 16 + w * 4 + qx0;
        int oy0 = wy * 4 + qy0 + SHIFT;     if (oy0 >= 192) oy0 -= 192;
        int oy1 = wy * 4 + qy0 + 2 + SHIFT; if (oy1 >= 192) oy1 -= 192;
        const int ddelta = (oy1 - oy0) * 192;
        int idx0[8];
        float prev0[8], prev1[8];
        #pragma unroll
        for (int d = 0; d < 8; ++d) {
            const int oc = half * 64 + ((d * 8 + h + SHIFT) & 63);
            idx0[d] = ((b * 128 + oc) * 192 + oy0) * 192 + ox;
            if (ACCUM) { prev0[d] = out[idx0[d]]; prev1[d] = out[idx0[d] + ddelta]; }
        }

        const int t0 = w * 16 + tqp, t1 = t0 + 8;
        h8v q0 = *reinterpret_cast<const h8v*>(&qs[t0 * 64 + (h ^ (t0 & 7)) * 8]);
        h8v q1 = *reinterpret_cast<const h8v*>(&qs[t1 * 64 + (h ^ (t1 & 7)) * 8]);
        const h2v* q0p = reinterpret_cast<const h2v*>(&q0);
        const h2v* q1p = reinterpret_cast<const h2v*>(&q1);

        // scores tightly bounded: exp2 without max-subtraction is safe
        h2v scp0[8], scp1[8];
        float den0 = 0.f, den1 = 0.f;
        #pragma unroll
        for (int tkp = 0; tkp < 8; ++tkp) {
            float e0[2], e1[2];
            #pragma unroll
            for (int u = 0; u < 2; ++u) {
                const int tk = tkp * 2 + u;
                const int kt = w * 16 + tk;
                h8v kr = *reinterpret_cast<const h8v*>(&ks[kt * 64 + (h ^ (kt & 7)) * 8]);
                const h2v* kp = reinterpret_cast<const h2v*>(&kr);
                float s0 = 0.f, s1 = 0.f;
                #pragma unroll
                for (int i = 0; i < 4; ++i) { s0 = dot2(q0p[i], kp[i], s0); s1 = dot2(q1p[i], kp[i], s1); }
                const int ky = tk >> 2, kx = tk & 3;
                s0 += bias_s[((qy0 - ky + 3) * 7 + (qx0 - kx + 3)) * 8 + h];
                s1 += bias_s[((qy0 + 2 - ky + 3) * 7 + (qx0 - kx + 3)) * 8 + h];
                e0[u] = fexp2(s0); e1[u] = fexp2(s1);
            }
            den0 += e0[0] + e0[1]; den1 += e1[0] + e1[1];
            scp0[tkp] = pk2h(e0[0], e0[1]);
            scp1[tkp] = pk2h(e1[0], e1[1]);
        }
        const float inv0 = 1.f / den0, inv1 = 1.f / den1;
        const h2v ip0 = pk2h(inv0, inv0), ip1 = pk2h(inv1, inv1);

        // ---- PV packed f16 (v_pk_fma_f16), normalized convex weights ----
        h2v o0pk[4], o1pk[4];
        #pragma unroll
        for (int j = 0; j < 4; ++j) { o0pk[j] = pk2h(0.f, 0.f); o1pk[j] = pk2h(0.f, 0.f); }
        #pragma unroll
        for (int tkp = 0; tkp < 8; ++tkp) {
            const h2v w0 = scp0[tkp] * ip0;
            const h2v w1 = scp1[tkp] * ip1;
            #pragma unroll
            for (int u = 0; u < 2; ++u) {
                const int tk = tkp * 2 + u;
                const int t = (1 + (tk >> 2)) * 6 + 1 + (tk & 3);
                h8v vr = *reinterpret_cast<const h8v*>(&vv[t * 64 + (h ^ (t & 7)) * 8]);
                const h2v* vp = reinterpret_cast<const h2v*>(&vr);
                h2v b0; b0[0] = w0[u]; b0[1] = w0[u];
                h2v b1; b1[0] = w1[u]; b1[1] = w1[u];
                #pragma unroll
                for (int j = 0; j < 4; ++j) {
                    o0pk[j] += b0 * vp[j];
                    o1pk[j] += b1 * vp[j];
                }
            }
        }

        // ---- lepe packed f16: lw layout [h][j][8 d] ----
        #pragma unroll
        for (int dy = 0; dy < 3; ++dy)
            #pragma unroll
            for (int dx = 0; dx < 3; ++dx) {
                const int ta = (qy0 + dy) * 6 + qx0 + dx;
                const int tb = ta + 12;                      // +2 rows for token 1
                h8v v0 = *reinterpret_cast<const h8v*>(&vv[ta * 64 + (h ^ (ta & 7)) * 8]);
                h8v v1 = *reinterpret_cast<const h8v*>(&vv[tb * 64 + (h ^ (tb & 7)) * 8]);
                h8v lw = *reinterpret_cast<const h8v*>(&lepe_s[(h * 9 + dy * 3 + dx) * 8]);
                const h2v* v0p = reinterpret_cast<const h2v*>(&v0);
                const h2v* v1p = reinterpret_cast<const h2v*>(&v1);
                const h2v* lwp = reinterpret_cast<const h2v*>(&lw);
                #pragma unroll
                for (int j = 0; j < 4; ++j) {
                    o0pk[j] += v0p[j] * lwp[j];
                    o1pk[j] += v1p[j] * lwp[j];
                }
            }

        #pragma unroll
        for (int d = 0; d < 8; ++d) {
            const float a0 = (float)o0pk[d >> 1][d & 1];
            const float a1 = (float)o1pk[d >> 1][d & 1];
            if (ACCUM) { out[idx0[d]] = prev0[d] + a0; out[idx0[d] + ddelta] = prev1[d] + a1; }
            else       { out[idx0[d]] = a0;            out[idx0[d] + ddelta] = a1; }
        }
    }
}

// ---------------- fallback (round-3 kernel, bf16; used only if ws too small) ----------------
template<int SHIFT, bool ACCUM>
__global__ __launch_bounds__(256) void swin_fb(
    const float* __restrict__ x, const float* __restrict__ qkv_w,
    const float* __restrict__ lepe_w, const float* __restrict__ bias_table,
    float* __restrict__ out)
{
    const int C = 128, HH = 192, WW = 192;
    const int win = blockIdx.x, wy = win / 48, wx = win % 48;
    const int half = blockIdx.y, b = blockIdx.z, tid = threadIdx.x;
    __shared__ short xpA[8 * 64 * 8];
    __shared__ float vs[64 * 37], qsf[64 * 17], ksf[64 * 17];
    __shared__ float bias_s[392], lepe_s[576];
    const int ys0 = wy * 4, xs0 = wx * 4;
    for (int i = tid; i < 392; i += 256) bias_s[i] = bias_table[i];
    for (int i = tid; i < 576; i += 256) lepe_s[i] = lepe_w[i];
    for (int item = tid; item < 512; item += 256) {
        const int slot = item >> 6, l = item & 63, kst = slot & 1;
        int p = 0; bool tvalid = true;
        if (slot < 6) { int t48 = (slot >> 1) * 16 + (l & 15); tvalid = (t48 < 36); p = t48; }
        else { int ti = l & 15; p = (1 + (ti >> 2)) * 6 + 1 + (ti & 3); }
        const int c0 = kst * 32 + (l >> 4) * 8;
        short8v pk;
        #pragma unroll
        for (int j = 0; j < 8; ++j) pk[j] = 0;
        if (tvalid) {
            int py = p / 6, px = p - py * 6;
            int ry = ys0 - 1 + py, rx = xs0 - 1 + px;
            if (ry >= 0 && ry < HH && rx >= 0 && rx < WW) {
                int oy = ry + SHIFT; if (oy >= HH) oy -= HH;
                #pragma unroll
                for (int j = 0; j < 8; ++j) {
                    int oc = half * 64 + c0 + j + SHIFT; if (oc >= C) oc -= C;
                    pk[j] = (short)f2bf(x[((b * C + oc) * HH + oy) * WW + rx]);
                }
            }
        }
        *reinterpret_cast<short8v*>(&xpA[item * 8]) = pk;
    }
    const int w = tid >> 6, l = tid & 63, nn = l & 15, g = l >> 4;
    short8v Bq[2], Bk[2], Bv[2];
    #pragma unroll
    for (int kst = 0; kst < 2; ++kst) {
        const int coff = kst * 32 + g * 8;
        const float* s0 = qkv_w + (w * 16 + nn) * 64 + coff;
        const float* s1 = qkv_w + (64 + w * 16 + nn) * 64 + coff;
        const float* s2 = qkv_w + (128 + w * 16 + nn) * 64 + coff;
        short8v p0, p1, p2;
        #pragma unroll
        for (int j = 0; j < 8; ++j) { p0[j] = (short)f2bf(s0[j]); p1[j] = (short)f2bf(s1[j]); p2[j] = (short)f2bf(s2[j]); }
        Bq[kst] = p0; Bk[kst] = p1; Bv[kst] = p2;
    }
    __syncthreads();
    {
        short8v Aq[2], Avf[3][2];
        #pragma unroll
        for (int kst = 0; kst < 2; ++kst)
            Aq[kst] = *reinterpret_cast<const short8v*>(&xpA[((6 + kst) * 64 + l) * 8]);
        #pragma unroll
        for (int mt = 0; mt < 3; ++mt)
            #pragma unroll
            for (int kst = 0; kst < 2; ++kst)
                Avf[mt][kst] = *reinterpret_cast<const short8v*>(&xpA[((mt * 2 + kst) * 64 + l) * 8]);
        f32x4 aQ = {0,0,0,0}, aK = {0,0,0,0}; f32x4 aV[3];
        #pragma unroll
        for (int mt = 0; mt < 3; ++mt) aV[mt] = (f32x4){0,0,0,0};
        #pragma unroll
        for (int kst = 0; kst < 2; ++kst) {
            aQ = __builtin_amdgcn_mfma_f32_16x16x32_bf16(Aq[kst], Bq[kst], aQ, 0, 0, 0);
            aK = __builtin_amdgcn_mfma_f32_16x16x32_bf16(Aq[kst], Bk[kst], aK, 0, 0, 0);
            #pragma unroll
            for (int mt = 0; mt < 3; ++mt)
                aV[mt] = __builtin_amdgcn_mfma_f32_16x16x32_bf16(Avf[mt][kst], Bv[kst], aV[mt], 0, 0, 0);
        }
        const int ch = w * 16 + nn;
        #pragma unroll
        for (int r = 0; r < 4; ++r) { qsf[ch * 17 + g * 4 + r] = aQ[r]; ksf[ch * 17 + g * 4 + r] = aK[r]; }
        #pragma unroll
        for (int mt = 0; mt < 3; ++mt)
            #pragma unroll
            for (int r = 0; r < 4; ++r) { int tok = mt * 16 + g * 4 + r; if (tok < 36) vs[ch * 37 + tok] = aV[mt][r]; }
    }
    __syncthreads();
    {
        const int tq = tid & 15, h = (tid >> 4) & 7, dh = tid >> 7;
        const int qy = tq >> 2, qx = tq & 3;
        const float scale = 0.35355339059327373f;
        float qreg[8];
        #pragma unroll
        for (int d = 0; d < 8; ++d) qreg[d] = qsf[(d * 8 + h) * 17 + tq] * scale;
        float sc[16]; float m = -1e30f;
        #pragma unroll
        for (int tk = 0; tk < 16; ++tk) {
            float s = 0.f;
            #pragma unroll
            for (int d = 0; d < 8; ++d) s += qreg[d] * ksf[(d * 8 + h) * 17 + tk];
            s += bias_s[((qy - (tk >> 2) + 3) * 7 + (qx - (tk & 3) + 3)) * 8 + h];
            sc[tk] = s; m = fmaxf(m, s);
        }
        float den = 0.f;
        #pragma unroll
        for (int tk = 0; tk < 16; ++tk) { sc[tk] = __expf(sc[tk] - m); den += sc[tk]; }
        const float inv = 1.f / den;
        float lw[4][9];
        #pragma unroll
        for (int dd = 0; dd < 4; ++dd) {
            int ch = (dh * 4 + dd) * 8 + h;
            #pragma unroll
            for (int j = 0; j < 9; ++j) lw[dd][j] = lepe_s[ch * 9 + j];
        }
        float o[4] = {0,0,0,0};
        #pragma unroll
        for (int tk = 0; tk < 16; ++tk) {
            int p = (1 + (tk >> 2)) * 6 + 1 + (tk & 3); float s = sc[tk];
            #pragma unroll
            for (int dd = 0; dd < 4; ++dd) o[dd] += s * vs[((dh * 4 + dd) * 8 + h) * 37 + p];
        }
        int oy = ys0 + qy + SHIFT; if (oy >= HH) oy -= HH;
        const int irx = xs0 + qx;
        #pragma unroll
        for (int dd = 0; dd < 4; ++dd) {
            const int ch = (dh * 4 + dd) * 8 + h;
            float val = o[dd] * inv;
            #pragma unroll
            for (int dy = 0; dy < 3; ++dy)
                #pragma unroll
                for (int dx = 0; dx < 3; ++dx)
                    val += vs[ch * 37 + (qy + dy) * 6 + (qx + dx)] * lw[dd][dy * 3 + dx];
            const int oc = half * 64 + ((ch + SHIFT) & 63);
            const int oidx = ((b * C + oc) * HH + oy) * WW + irx;
            if (ACCUM) out[oidx] += val; else out[oidx] = val;
        }
    }
}

extern "C" void kernel_launch(void* const* d_in, const int* in_sizes, int n_in,
                              void* d_out, int out_size, void* d_ws, size_t ws_size,
                              hipStream_t stream) {
    const float* x          = (const float*)d_in[0];
    const float* qkv_w      = (const float*)d_in[1];
    const float* lepe_w     = (const float*)d_in[2];
    const float* bias_table = (const float*)d_in[3];
    float* out = (float*)d_out;

    const size_t XBF_BYTES = 8UL * 192 * 192 * 128 * 2;        // 75,497,472
    const size_t NEED = 32768 + 2 * XBF_BYTES;

    if (ws_size >= NEED) {
        __fp16* wf   = (__fp16*)d_ws;
        __fp16* xbf0 = (__fp16*)((char*)d_ws + 32768);
        __fp16* xbf2 = (__fp16*)((char*)d_ws + 32768 + XBF_BYTES);
        prep_weights<<<6, 256, 0, stream>>>(qkv_w, wf);
        prep_x<<<dim3(6, 192, 8), 256, 0, stream>>>(x, xbf0, xbf2);
        dim3 grid(576, 2, 8);
        swin_main<0, false><<<grid, 256, 0, stream>>>(xbf0, wf, lepe_w, bias_table, out);
        swin_main<2, true ><<<grid, 256, 0, stream>>>(xbf2, wf, lepe_w, bias_table, out);
    } else {
        dim3 grid(48 * 48, 2, 8);
        swin_fb<0, false><<<grid, 256, 0, stream>>>(x, qkv_w, lepe_w, bias_table, out);
        swin_fb<2, true ><<<grid, 256, 0, stream>>>(x, qkv_w, lepe_w, bias_table, out);
    }
}

// Round 13
// 322.868 us; speedup vs baseline: 1.2474x; 1.1709x over previous
//
#include <hip/hip_runtime.h>

typedef __attribute__((ext_vector_type(8))) short short8v;   // 8 bf16 (fallback)
typedef __attribute__((ext_vector_type(8))) __fp16 h8v;      // 8 f16
typedef __attribute__((ext_vector_type(2))) __fp16 h2v;      // 2 f16
typedef __attribute__((ext_vector_type(4))) float f32x4;

__device__ inline unsigned short f2bf(float f) {
    unsigned u = __builtin_bit_cast(unsigned, f);
    return (unsigned short)((u + 0x7FFFu + ((u >> 16) & 1u)) >> 16);   // RNE
}

__device__ inline float dot2(h2v a, h2v b, float c) {
#if __has_builtin(__builtin_amdgcn_fdot2)
    return __builtin_amdgcn_fdot2(a, b, c, false);
#else
    return c + (float)a[0] * (float)b[0] + (float)a[1] * (float)b[1];
#endif
}
__device__ inline h2v pk2h(float a, float b) {
#if __has_builtin(__builtin_amdgcn_cvt_pkrtz)
    return __builtin_bit_cast(h2v, __builtin_amdgcn_cvt_pkrtz(a, b));
#else
    h2v r; r[0] = (__fp16)a; r[1] = (__fp16)b; return r;
#endif
}
__device__ inline float fexp2(float x) {
#if __has_builtin(__builtin_amdgcn_exp2f)
    return __builtin_amdgcn_exp2f(x);
#else
    return __expf(x * 0.6931471805599453f);
#endif
}

// ---------------- prep 1: qkv_w -> f16 B-fragments in ws ----------------
__global__ __launch_bounds__(256) void prep_weights(const float* __restrict__ qkv_w,
                                                    __fp16* __restrict__ wf) {
    int it = blockIdx.x * 256 + threadIdx.x;      // 1536 items
    if (it >= 1536) return;
    int l = it & 63, frag = it >> 6;
    int which = frag >> 3, nt = (frag >> 1) & 3, kst = frag & 1;
    const float* src = qkv_w + (which * 64 + nt * 16 + (l & 15)) * 64 + kst * 32 + (l >> 4) * 8;
    h8v pk;
    #pragma unroll
    for (int j = 0; j < 8; ++j) pk[j] = (__fp16)src[j];
    *reinterpret_cast<h8v*>(wf + it * 8) = pk;
}

// ---------------- prep 2: x (b,c,y,x) fp32 -> ONE (b,y,x,128) f16 buffer, no roll ----------------
// 75.5 MB; working set (xh + out) = 226 MB < 256 MB L3 -> steady-state L3-resident.
__global__ __launch_bounds__(256) void prep_x(const float* __restrict__ x,
                                              __fp16* __restrict__ xh) {
    const int xt = blockIdx.x;   // 0..5 (32-wide tiles)
    const int y  = blockIdx.y;
    const int b  = blockIdx.z;
    const int x0 = xt * 32;
    __shared__ float buf[128 * 33];

    for (int it = threadIdx.x; it < 1024; it += 256) {
        int c = it >> 3, xq = it & 7;
        const float4 v = *reinterpret_cast<const float4*>(
            x + ((b * 128 + c) * 192 + y) * 192 + x0 + xq * 4);
        float* d = &buf[c * 33 + xq * 4];
        d[0] = v.x; d[1] = v.y; d[2] = v.z; d[3] = v.w;
    }
    __syncthreads();

    for (int it = threadIdx.x; it < 512; it += 256) {
        int xl = it >> 4, c8 = it & 15;
        h8v pk;
        #pragma unroll
        for (int j = 0; j < 8; ++j) pk[j] = (__fp16)buf[(c8 * 8 + j) * 33 + xl];
        *reinterpret_cast<h8v*>(xh + (((size_t)(b * 192 + y) * 192) + x0 + xl) * 128 + c8 * 8) = pk;
    }
}

// ---------------- main: 4-window strip per block ----------------
template<int SHIFT, bool ACCUM>
__global__ __launch_bounds__(256) void swin_main(
    const __fp16* __restrict__ xbf,   // (b,y,x,128) f16, unrolled (shared by both shifts)
    const __fp16* __restrict__ wfrag,
    const float* __restrict__ lepe_w,
    const float* __restrict__ bias_table,
    float* __restrict__ out)
{
    const int bx = blockIdx.x;                 // wy*12 + strip
    const int wy = bx / 12, strip = bx % 12;
    const int half = blockIdx.y, b = blockIdx.z;
    const int tid = threadIdx.x;
    const int w = tid >> 6, l = tid & 63;      // wave = window within strip

    // pool phase A: x strip [108 pos][64 ch]; phase B: wave-private v [4 w][36 t][64 ch]
    __shared__ __fp16 pool[9216];              // 18432 B
    __shared__ __fp16 qs[64 * 64];             // q [tok][ch' head-major] swz, pre-scaled*log2e
    __shared__ __fp16 ks[64 * 64];
    __shared__ float  bias_s[392];             // pre-scaled by log2e
    __shared__ __fp16 lepe_s[576];             // layout [h][3x3 j][8 d]
    // LDS total = 37536 B -> 4 blocks/CU

    for (int i = tid; i < 392; i += 256) bias_s[i] = bias_table[i] * 1.4426950408889634f;
    for (int i = tid; i < 576; i += 256) {
        int d = i & 7, rest = i >> 3;
        int j = rest % 9, h = rest / 9;
        lepe_s[i] = (__fp16)lepe_w[(d * 8 + h) * 9 + j];
    }

    // ---- stage strip; roll applied here: row = (ry+SHIFT)%192, channel +SHIFT via dword recompose ----
    const int ry0 = wy * 4 - 1, rx0 = strip * 16 - 1;
    for (int it = tid; it < 864; it += 256) {
        const int pos = it >> 3, slot = it & 7;
        const int py = pos / 18, px = pos - py * 18;
        const int ry = ry0 + py, rx = rx0 + px;
        h8v val;
        #pragma unroll
        for (int j = 0; j < 8; ++j) val[j] = (__fp16)0.f;
        if (ry >= 0 && ry < 192 && rx >= 0 && rx < 192) {
            int phys = ry + SHIFT; if (phys >= 192) phys -= 192;
            const int srcslot = slot ^ (pos & 7);
            const __fp16* base = xbf + (((size_t)(b * 192 + phys) * 192) + rx) * 128;
            if constexpr (SHIFT == 0) {
                val = *reinterpret_cast<const h8v*>(base + half * 64 + srcslot * 8);
            } else {
                // channels (half*64 + srcslot*8 + 2 .. +9) mod 128 == dwords {A.y,A.z,A.w,B}
                int4 A = *reinterpret_cast<const int4*>(base + half * 64 + srcslot * 8);
                const int boff = (half * 64 + srcslot * 8 + 8) & 127;   // wrap at channel 128
                int B = *reinterpret_cast<const int*>(base + boff);
                int4 R; R.x = A.y; R.y = A.z; R.z = A.w; R.w = B;
                val = __builtin_bit_cast(h8v, R);
            }
        }
        *reinterpret_cast<h8v*>(&pool[pos * 64 + slot * 8]) = val;
    }
    __syncthreads();

    // ---- A fragments (swizzled reads from strip) ----
    const int tok16 = l & 15, g = l >> 4;
    h8v Aq[2], Av[3][2];
    {
        const int posq = (1 + (tok16 >> 2)) * 18 + w * 4 + 1 + (tok16 & 3);
        #pragma unroll
        for (int kst = 0; kst < 2; ++kst) {
            int chunk = (kst * 4 + g) ^ (posq & 7);
            Aq[kst] = *reinterpret_cast<const h8v*>(&pool[posq * 64 + chunk * 8]);
        }
        #pragma unroll
        for (int mt = 0; mt < 3; ++mt) {
            int t = mt * 16 + tok16;
            int posv = (t < 36) ? ((t / 6) * 18 + w * 4 + (t % 6)) : 0;
            #pragma unroll
            for (int kst = 0; kst < 2; ++kst) {
                int chunk = (kst * 4 + g) ^ (posv & 7);
                Av[mt][kst] = *reinterpret_cast<const h8v*>(&pool[posv * 64 + chunk * 8]);
            }
        }
    }
    __syncthreads();   // strip dead; pool becomes wave-private v

    // ---- MFMA + scatter; channels stored head-major ch'=(ch&7)*8+(ch>>3) ----
    #pragma unroll
    for (int nt = 0; nt < 4; ++nt) {
        h8v Bq[2], Bk[2], Bv[2];
        #pragma unroll
        for (int kst = 0; kst < 2; ++kst) {
            Bq[kst] = *reinterpret_cast<const h8v*>(wfrag + (((0 * 8 + nt * 2 + kst) * 64 + l) * 8));
            Bk[kst] = *reinterpret_cast<const h8v*>(wfrag + (((1 * 8 + nt * 2 + kst) * 64 + l) * 8));
            Bv[kst] = *reinterpret_cast<const h8v*>(wfrag + (((2 * 8 + nt * 2 + kst) * 64 + l) * 8));
        }
        f32x4 aQ = {0.f,0.f,0.f,0.f}, aK = {0.f,0.f,0.f,0.f};
        f32x4 aV[3];
        #pragma unroll
        for (int mt = 0; mt < 3; ++mt) aV[mt] = (f32x4){0.f,0.f,0.f,0.f};
        #pragma unroll
        for (int kst = 0; kst < 2; ++kst) {
            aQ = __builtin_amdgcn_mfma_f32_16x16x32_f16(Aq[kst], Bq[kst], aQ, 0, 0, 0);
            aK = __builtin_amdgcn_mfma_f32_16x16x32_f16(Aq[kst], Bk[kst], aK, 0, 0, 0);
            #pragma unroll
            for (int mt = 0; mt < 3; ++mt)
                aV[mt] = __builtin_amdgcn_mfma_f32_16x16x32_f16(Av[mt][kst], Bv[kst], aV[mt], 0, 0, 0);
        }
        const int ch  = nt * 16 + tok16;
        const int chp = (ch & 7) * 8 + (ch >> 3);
        #pragma unroll
        for (int r = 0; r < 4; ++r) {
            const int qtok = w * 16 + 4 * g + r;
            const int pb = (((chp >> 3) ^ (qtok & 7)) * 8 + (chp & 7));
            // q pre-scaled by 8^-0.5 * log2(e) so scores are in log2 units
            qs[qtok * 64 + pb] = (__fp16)(aQ[r] * 0.5101293f);
            ks[qtok * 64 + pb] = (__fp16)aK[r];
        }
        #pragma unroll
        for (int mt = 0; mt < 3; ++mt)
            #pragma unroll
            for (int r = 0; r < 4; ++r) {
                const int t = mt * 16 + 4 * g + r;       // linear token in wave's 6x6 patch
                if (t < 36) {
                    const int pb = (((chp >> 3) ^ (t & 7)) * 8 + (chp & 7));
                    pool[(w * 36 + t) * 64 + pb] = (__fp16)aV[mt][r];
                }
            }
    }
    __syncthreads();

    // ---- attention + lepe + store: wave = window, lane = (h, tq&7), 2 query tokens/lane ----
    {
        const int h = l >> 3, tqp = l & 7;
        const int qy0 = tqp >> 2, qx0 = tqp & 3;   // tq0 = tqp; tq1 = tqp+8 -> qy0+2, qx0
        const __fp16* vv = &pool[w * 36 * 64];

        // output indices + RMW prefetch (latency hides under QK/PV)
        const int ox = strip * 16 + w * 4 + qx0;
        int oy0 = wy * 4 + qy0 + SHIFT;     if (oy0 >= 192) oy0 -= 192;
        int oy1 = wy * 4 + qy0 + 2 + SHIFT; if (oy1 >= 192) oy1 -= 192;
        const int ddelta = (oy1 - oy0) * 192;
        int idx0[8];
        float prev0[8], prev1[8];
        #pragma unroll
        for (int d = 0; d < 8; ++d) {
            const int oc = half * 64 + ((d * 8 + h + SHIFT) & 63);
            idx0[d] = ((b * 128 + oc) * 192 + oy0) * 192 + ox;
            if (ACCUM) { prev0[d] = out[idx0[d]]; prev1[d] = out[idx0[d] + ddelta]; }
        }

        const int t0 = w * 16 + tqp, t1 = t0 + 8;
        h8v q0 = *reinterpret_cast<const h8v*>(&qs[t0 * 64 + (h ^ (t0 & 7)) * 8]);
        h8v q1 = *reinterpret_cast<const h8v*>(&qs[t1 * 64 + (h ^ (t1 & 7)) * 8]);
        const h2v* q0p = reinterpret_cast<const h2v*>(&q0);
        const h2v* q1p = reinterpret_cast<const h2v*>(&q1);

        // scores tightly bounded: exp2 without max-subtraction is safe
        h2v scp0[8], scp1[8];
        float den0 = 0.f, den1 = 0.f;
        #pragma unroll
        for (int tkp = 0; tkp < 8; ++tkp) {
            float e0[2], e1[2];
            #pragma unroll
            for (int u = 0; u < 2; ++u) {
                const int tk = tkp * 2 + u;
                const int kt = w * 16 + tk;
                h8v kr = *reinterpret_cast<const h8v*>(&ks[kt * 64 + (h ^ (kt & 7)) * 8]);
                const h2v* kp = reinterpret_cast<const h2v*>(&kr);
                float s0 = 0.f, s1 = 0.f;
                #pragma unroll
                for (int i = 0; i < 4; ++i) { s0 = dot2(q0p[i], kp[i], s0); s1 = dot2(q1p[i], kp[i], s1); }
                const int ky = tk >> 2, kx = tk & 3;
                s0 += bias_s[((qy0 - ky + 3) * 7 + (qx0 - kx + 3)) * 8 + h];
                s1 += bias_s[((qy0 + 2 - ky + 3) * 7 + (qx0 - kx + 3)) * 8 + h];
                e0[u] = fexp2(s0); e1[u] = fexp2(s1);
            }
            den0 += e0[0] + e0[1]; den1 += e1[0] + e1[1];
            scp0[tkp] = pk2h(e0[0], e0[1]);
            scp1[tkp] = pk2h(e1[0], e1[1]);
        }
        const float inv0 = 1.f / den0, inv1 = 1.f / den1;
        const h2v ip0 = pk2h(inv0, inv0), ip1 = pk2h(inv1, inv1);

        // ---- PV packed f16 (v_pk_fma_f16), normalized convex weights ----
        h2v o0pk[4], o1pk[4];
        #pragma unroll
        for (int j = 0; j < 4; ++j) { o0pk[j] = pk2h(0.f, 0.f); o1pk[j] = pk2h(0.f, 0.f); }
        #pragma unroll
        for (int tkp = 0; tkp < 8; ++tkp) {
            const h2v w0 = scp0[tkp] * ip0;
            const h2v w1 = scp1[tkp] * ip1;
            #pragma unroll
            for (int u = 0; u < 2; ++u) {
                const int tk = tkp * 2 + u;
                const int t = (1 + (tk >> 2)) * 6 + 1 + (tk & 3);
                h8v vr = *reinterpret_cast<const h8v*>(&vv[t * 64 + (h ^ (t & 7)) * 8]);
                const h2v* vp = reinterpret_cast<const h2v*>(&vr);
                h2v b0; b0[0] = w0[u]; b0[1] = w0[u];
                h2v b1; b1[0] = w1[u]; b1[1] = w1[u];
                #pragma unroll
                for (int j = 0; j < 4; ++j) {
                    o0pk[j] += b0 * vp[j];
                    o1pk[j] += b1 * vp[j];
                }
            }
        }

        // ---- lepe packed f16: lw layout [h][j][8 d] ----
        #pragma unroll
        for (int dy = 0; dy < 3; ++dy)
            #pragma unroll
            for (int dx = 0; dx < 3; ++dx) {
                const int ta = (qy0 + dy) * 6 + qx0 + dx;
                const int tb = ta + 12;                      // +2 rows for token 1
                h8v v0 = *reinterpret_cast<const h8v*>(&vv[ta * 64 + (h ^ (ta & 7)) * 8]);
                h8v v1 = *reinterpret_cast<const h8v*>(&vv[tb * 64 + (h ^ (tb & 7)) * 8]);
                h8v lw = *reinterpret_cast<const h8v*>(&lepe_s[(h * 9 + dy * 3 + dx) * 8]);
                const h2v* v0p = reinterpret_cast<const h2v*>(&v0);
                const h2v* v1p = reinterpret_cast<const h2v*>(&v1);
                const h2v* lwp = reinterpret_cast<const h2v*>(&lw);
                #pragma unroll
                for (int j = 0; j < 4; ++j) {
                    o0pk[j] += v0p[j] * lwp[j];
                    o1pk[j] += v1p[j] * lwp[j];
                }
            }

        #pragma unroll
        for (int d = 0; d < 8; ++d) {
            const float a0 = (float)o0pk[d >> 1][d & 1];
            const float a1 = (float)o1pk[d >> 1][d & 1];
            if (ACCUM) { out[idx0[d]] = prev0[d] + a0; out[idx0[d] + ddelta] = prev1[d] + a1; }
            else       { out[idx0[d]] = a0;            out[idx0[d] + ddelta] = a1; }
        }
    }
}

// ---------------- fallback (round-3 kernel, bf16; used only if ws too small) ----------------
template<int SHIFT, bool ACCUM>
__global__ __launch_bounds__(256) void swin_fb(
    const float* __restrict__ x, const float* __restrict__ qkv_w,
    const float* __restrict__ lepe_w, const float* __restrict__ bias_table,
    float* __restrict__ out)
{
    const int C = 128, HH = 192, WW = 192;
    const int win = blockIdx.x, wy = win / 48, wx = win % 48;
    const int half = blockIdx.y, b = blockIdx.z, tid = threadIdx.x;
    __shared__ short xpA[8 * 64 * 8];
    __shared__ float vs[64 * 37], qsf[64 * 17], ksf[64 * 17];
    __shared__ float bias_s[392], lepe_s[576];
    const int ys0 = wy * 4, xs0 = wx * 4;
    for (int i = tid; i < 392; i += 256) bias_s[i] = bias_table[i];
    for (int i = tid; i < 576; i += 256) lepe_s[i] = lepe_w[i];
    for (int item = tid; item < 512; item += 256) {
        const int slot = item >> 6, l = item & 63, kst = slot & 1;
        int p = 0; bool tvalid = true;
        if (slot < 6) { int t48 = (slot >> 1) * 16 + (l & 15); tvalid = (t48 < 36); p = t48; }
        else { int ti = l & 15; p = (1 + (ti >> 2)) * 6 + 1 + (ti & 3); }
        const int c0 = kst * 32 + (l >> 4) * 8;
        short8v pk;
        #pragma unroll
        for (int j = 0; j < 8; ++j) pk[j] = 0;
        if (tvalid) {
            int py = p / 6, px = p - py * 6;
            int ry = ys0 - 1 + py, rx = xs0 - 1 + px;
            if (ry >= 0 && ry < HH && rx >= 0 && rx < WW) {
                int oy = ry + SHIFT; if (oy >= HH) oy -= HH;
                #pragma unroll
                for (int j = 0; j < 8; ++j) {
                    int oc = half * 64 + c0 + j + SHIFT; if (oc >= C) oc -= C;
                    pk[j] = (short)f2bf(x[((b * C + oc) * HH + oy) * WW + rx]);
                }
            }
        }
        *reinterpret_cast<short8v*>(&xpA[item * 8]) = pk;
    }
    const int w = tid >> 6, l = tid & 63, nn = l & 15, g = l >> 4;
    short8v Bq[2], Bk[2], Bv[2];
    #pragma unroll
    for (int kst = 0; kst < 2; ++kst) {
        const int coff = kst * 32 + g * 8;
        const float* s0 = qkv_w + (w * 16 + nn) * 64 + coff;
        const float* s1 = qkv_w + (64 + w * 16 + nn) * 64 + coff;
        const float* s2 = qkv_w + (128 + w * 16 + nn) * 64 + coff;
        short8v p0, p1, p2;
        #pragma unroll
        for (int j = 0; j < 8; ++j) { p0[j] = (short)f2bf(s0[j]); p1[j] = (short)f2bf(s1[j]); p2[j] = (short)f2bf(s2[j]); }
        Bq[kst] = p0; Bk[kst] = p1; Bv[kst] = p2;
    }
    __syncthreads();
    {
        short8v Aq[2], Avf[3][2];
        #pragma unroll
        for (int kst = 0; kst < 2; ++kst)
            Aq[kst] = *reinterpret_cast<const short8v*>(&xpA[((6 + kst) * 64 + l) * 8]);
        #pragma unroll
        for (int mt = 0; mt < 3; ++mt)
            #pragma unroll
            for (int kst = 0; kst < 2; ++kst)
                Avf[mt][kst] = *reinterpret_cast<const short8v*>(&xpA[((mt * 2 + kst) * 64 + l) * 8]);
        f32x4 aQ = {0,0,0,0}, aK = {0,0,0,0}; f32x4 aV[3];
        #pragma unroll
        for (int mt = 0; mt < 3; ++mt) aV[mt] = (f32x4){0,0,0,0};
        #pragma unroll
        for (int kst = 0; kst < 2; ++kst) {
            aQ = __builtin_amdgcn_mfma_f32_16x16x32_bf16(Aq[kst], Bq[kst], aQ, 0, 0, 0);
            aK = __builtin_amdgcn_mfma_f32_16x16x32_bf16(Aq[kst], Bk[kst], aK, 0, 0, 0);
            #pragma unroll
            for (int mt = 0; mt < 3; ++mt)
                aV[mt] = __builtin_amdgcn_mfma_f32_16x16x32_bf16(Avf[mt][kst], Bv[kst], aV[mt], 0, 0, 0);
        }
        const int ch = w * 16 + nn;
        #pragma unroll
        for (int r = 0; r < 4; ++r) { qsf[ch * 17 + g * 4 + r] = aQ[r]; ksf[ch * 17 + g * 4 + r] = aK[r]; }
        #pragma unroll
        for (int mt = 0; mt < 3; ++mt)
            #pragma unroll
            for (int r = 0; r < 4; ++r) { int tok = mt * 16 + g * 4 + r; if (tok < 36) vs[ch * 37 + tok] = aV[mt][r]; }
    }
    __syncthreads();
    {
        const int tq = tid & 15, h = (tid >> 4) & 7, dh = tid >> 7;
        const int qy = tq >> 2, qx = tq & 3;
        const float scale = 0.35355339059327373f;
        float qreg[8];
        #pragma unroll
        for (int d = 0; d < 8; ++d) qreg[d] = qsf[(d * 8 + h) * 17 + tq] * scale;
        float sc[16]; float m = -1e30f;
        #pragma unroll
        for (int tk = 0; tk < 16; ++tk) {
            float s = 0.f;
            #pragma unroll
            for (int d = 0; d < 8; ++d) s += qreg[d] * ksf[(d * 8 + h) * 17 + tk];
            s += bias_s[((qy - (tk >> 2) + 3) * 7 + (qx - (tk & 3) + 3)) * 8 + h];
            sc[tk] = s; m = fmaxf(m, s);
        }
        float den = 0.f;
        #pragma unroll
        for (int tk = 0; tk < 16; ++tk) { sc[tk] = __expf(sc[tk] - m); den += sc[tk]; }
        const float inv = 1.f / den;
        float lw[4][9];
        #pragma unroll
        for (int dd = 0; dd < 4; ++dd) {
            int ch = (dh * 4 + dd) * 8 + h;
            #pragma unroll
            for (int j = 0; j < 9; ++j) lw[dd][j] = lepe_s[ch * 9 + j];
        }
        float o[4] = {0,0,0,0};
        #pragma unroll
        for (int tk = 0; tk < 16; ++tk) {
            int p = (1 + (tk >> 2)) * 6 + 1 + (tk & 3); float s = sc[tk];
            #pragma unroll
            for (int dd = 0; dd < 4; ++dd) o[dd] += s * vs[((dh * 4 + dd) * 8 + h) * 37 + p];
        }
        int oy = ys0 + qy + SHIFT; if (oy >= HH) oy -= HH;
        const int irx = xs0 + qx;
        #pragma unroll
        for (int dd = 0; dd < 4; ++dd) {
            const int ch = (dh * 4 + dd) * 8 + h;
            float val = o[dd] * inv;
            #pragma unroll
            for (int dy = 0; dy < 3; ++dy)
                #pragma unroll
                for (int dx = 0; dx < 3; ++dx)
                    val += vs[ch * 37 + (qy + dy) * 6 + (qx + dx)] * lw[dd][dy * 3 + dx];
            const int oc = half * 64 + ((ch + SHIFT) & 63);
            const int oidx = ((b * C + oc) * HH + oy) * WW + irx;
            if (ACCUM) out[oidx] += val; else out[oidx] = val;
        }
    }
}

extern "C" void kernel_launch(void* const* d_in, const int* in_sizes, int n_in,
                              void* d_out, int out_size, void* d_ws, size_t ws_size,
                              hipStream_t stream) {
    const float* x          = (const float*)d_in[0];
    const float* qkv_w      = (const float*)d_in[1];
    const float* lepe_w     = (const float*)d_in[2];
    const float* bias_table = (const float*)d_in[3];
    float* out = (float*)d_out;

    const size_t XH_BYTES = 8UL * 192 * 192 * 128 * 2;         // 75,497,472
    const size_t NEED = 32768 + XH_BYTES;

    if (ws_size >= NEED) {
        __fp16* wf = (__fp16*)d_ws;
        __fp16* xh = (__fp16*)((char*)d_ws + 32768);
        prep_weights<<<6, 256, 0, stream>>>(qkv_w, wf);
        prep_x<<<dim3(6, 192, 8), 256, 0, stream>>>(x, xh);
        dim3 grid(576, 2, 8);
        swin_main<0, false><<<grid, 256, 0, stream>>>(xh, wf, lepe_w, bias_table, out);
        swin_main<2, true ><<<grid, 256, 0, stream>>>(xh, wf, lepe_w, bias_table, out);
    } else {
        dim3 grid(48 * 48, 2, 8);
        swin_fb<0, false><<<grid, 256, 0, stream>>>(x, qkv_w, lepe_w, bias_table, out);
        swin_fb<2, true ><<<grid, 256, 0, stream>>>(x, qkv_w, lepe_w, bias_table, out);
    }
}